// Round 21
// baseline (1263.956 us; speedup 1.0000x reference)
//
#include <hip/hip_runtime.h>
#include <hip/hip_bf16.h>
#include <math.h>

#define B    64
#define T    256
#define H    1024
#define G4   4096
#define TC   32           // timesteps per x_proj chunk (double-buffered)
#define NCH  (T / TC)
#define NBLK 128          // recurrence blocks (8 h-cols each)
#define NSLOT (TC + 1)    // hchain slots; slot(t) = t % NSLOT
#define FSTR 16           // flag stride in ints (64B apart)

typedef __attribute__((ext_vector_type(8))) short bf16x8;
typedef __attribute__((ext_vector_type(4))) float f32x4;

__device__ __forceinline__ unsigned short f2bf(float x) {
    union { float f; unsigned u; } v; v.f = x;
    unsigned r = v.u + 0x7fffu + ((v.u >> 16) & 1u);   // RNE
    return (unsigned short)(r >> 16);
}
__device__ __forceinline__ float bf2f(unsigned short s) {
    union { unsigned u; float f; } v; v.u = ((unsigned)s) << 16;
    return v.f;
}
__device__ __forceinline__ float sigm_f(float x) {
    return 1.f / (1.f + __expf(-x));
}
__device__ __forceinline__ float tanh_f(float x) {
    float e = __expf(2.f * x);
    return (e - 1.f) / (e + 1.f);
}
__device__ __forceinline__ bf16x8 pack8(float4 a0, float4 a1) {
    bf16x8 o;
    o[0] = f2bf(a0.x); o[1] = f2bf(a0.y); o[2] = f2bf(a0.z); o[3] = f2bf(a0.w);
    o[4] = f2bf(a1.x); o[5] = f2bf(a1.y); o[6] = f2bf(a1.z); o[7] = f2bf(a1.w);
    return o;
}

// ---------------------------------------------------------------------------
// one 128x128 x_proj tile; embedding gather AND both f32->bf16 casts fused
// into staging (A from emb f32, B from Wih f32). 256 threads (t256).
// ---------------------------------------------------------------------------
__device__ __forceinline__ void xproj_tile(
    const int* __restrict__ tgt, const float* __restrict__ emb,
    const float* __restrict__ Wih, unsigned short* __restrict__ C,
    int t0, int brow, int bcol,
    unsigned short* AsB, int* toks, int t256)
{
    unsigned short* As = AsB;
    unsigned short* Bs = AsB + 128 * 64;
    const int w = t256 >> 6, lane = t256 & 63;
    const int wr = w >> 1, wc = w & 1;
    const int lr = lane & 15, lg = lane >> 4;

    if (t256 < 128) {
        int r = brow + t256;                   // A row = tc*B + b
        toks[t256] = tgt[(r & 63) * T + t0 + (r >> 6)];
    }
    __syncthreads();

    f32x4 acc[4][4] = {};

    for (int kc = 0; kc < H; kc += 64) {
        if (kc) __syncthreads();
        #pragma unroll
        for (int i = 0; i < 4; ++i) {
            int sf  = i * 256 + t256;
            int row = sf >> 3, s = sf & 7;
            int col = kc + s * 8;
            const float4* sa = (const float4*)(emb
                + (size_t)toks[row] * H + col);
            *(bf16x8*)(As + row * 64 + ((s ^ (row & 7)) * 8)) =
                pack8(sa[0], sa[1]);
            const float4* sb = (const float4*)(Wih
                + (size_t)(bcol + row) * H + col);
            *(bf16x8*)(Bs + row * 64 + ((s ^ (row & 7)) * 8)) =
                pack8(sb[0], sb[1]);
        }
        __syncthreads();
        #pragma unroll
        for (int kk = 0; kk < 2; ++kk) {
            bf16x8 af[4], bv[4];
            #pragma unroll
            for (int m = 0; m < 4; ++m) {
                int row = wr * 64 + m * 16 + lr;
                int s   = kk * 4 + lg;
                af[m] = *(const bf16x8*)(As + row * 64 + ((s ^ (row & 7)) * 8));
            }
            #pragma unroll
            for (int n = 0; n < 4; ++n) {
                int row = wc * 64 + n * 16 + lr;
                int s   = kk * 4 + lg;
                bv[n] = *(const bf16x8*)(Bs + row * 64 + ((s ^ (row & 7)) * 8));
            }
            #pragma unroll
            for (int m = 0; m < 4; ++m)
                #pragma unroll
                for (int n = 0; n < 4; ++n)
                    acc[m][n] = __builtin_amdgcn_mfma_f32_16x16x32_bf16(
                        af[m], bv[n], acc[m][n], 0, 0, 0);
        }
    }
    #pragma unroll
    for (int m = 0; m < 4; ++m)
        #pragma unroll
        for (int n = 0; n < 4; ++n)
            #pragma unroll
            for (int r = 0; r < 4; ++r) {
                int row = brow + wr * 64 + m * 16 + lg * 4 + r;
                int col = bcol + wc * 64 + n * 16 + lr;
                C[(size_t)row * G4 + col] = f2bf(acc[m][n][r]);
            }
    __syncthreads();   // LDS safe for next tile
}

// ---------------------------------------------------------------------------
// standalone prologue GEMM for chunk 0: 512 blocks x 256 thr, 1 tile each
// ---------------------------------------------------------------------------
__global__ __launch_bounds__(256) void gemm_xproj(
    const int* __restrict__ tgt, const float* __restrict__ emb,
    const float* __restrict__ Wih, unsigned short* __restrict__ xp,
    int t0)
{
    __shared__ __align__(16) unsigned char smem[33280];
    unsigned short* AsB = (unsigned short*)smem;
    int* toks = (int*)(smem + 32768);
    int tile = blockIdx.x;                      // 0..511
    xproj_tile(tgt, emb, Wih, xp, t0,
               (tile >> 5) * 128, (tile & 31) * 128, AsB, toks, threadIdx.x);
}

// ---------------------------------------------------------------------------
// fused dual-role cooperative kernel (r20 structure; weights read f32,
// casts inline):
//  blocks 0..127  — r17 recurrence for chunk at t0 (slot ring t % 33);
//  blocks 128..255 — next chunk's x_proj GEMM into xpn.
// ---------------------------------------------------------------------------
__global__ __launch_bounds__(512) void lstm_fused(
    const unsigned short* __restrict__ xproj,  // [TC][B][4096] bf16 (cur)
    const float* __restrict__ Whh,             // [4096][1024] f32
    const float* __restrict__ bih, const float* __restrict__ bhh,
    unsigned short* __restrict__ hchain,       // [NSLOT][NBLK][64][8] bf16
    float* __restrict__ cbuf,                  // [B][H] f32
    float* __restrict__ outputs,               // [B][T][H] f32
    int* __restrict__ flags,                   // [NBLK*FSTR]
    int t0,
    const int* __restrict__ tgt, const float* __restrict__ emb,
    const float* __restrict__ Wih,             // [4096][1024] f32
    unsigned short* __restrict__ xpn,          // next chunk's xproj out
    int t0n, int do_gemm)
{
    __shared__ __align__(16) unsigned char smem[83968];
    const int tid = threadIdx.x;
    const int bid = blockIdx.x;

    if (bid >= NBLK) {
        // ================= GEMM role =================
        if (!do_gemm) return;
        const int sub  = tid >> 8;             // 0,1
        const int t256 = tid & 255;
        unsigned char* base = smem + sub * 33280;
        unsigned short* AsB = (unsigned short*)base;
        int* toks = (int*)(base + 32768);
        const int gb = bid - NBLK;             // 0..127
        #pragma unroll
        for (int i = 0; i < 2; ++i) {
            int tile = i * 256 + gb * 2 + sub; // 0..511
            xproj_tile(tgt, emb, Wih, xpn, t0n,
                       (tile >> 5) * 128, (tile & 31) * 128, AsB, toks, t256);
        }
        return;
    }

    // ================= recurrence role (r17 verbatim) =================
    bf16x8* Ws = (bf16x8*)smem;                        // 64 KB
    float (*gst)[64][36] = (float (*)[64][36])(smem + 65536);  // 18.4 KB

    const int jb = bid;
    const int j0 = jb * 8;

    // stage W_hh slice from f32 (cast inline): rows v = q*8+jc
    #pragma unroll
    for (int it = 0; it < 8; ++it) {
        int f = it * 512 + tid;                // 16B-slot id, 0..4095
        int v = f >> 7, s = f & 127;
        int grow = (v >> 3) * H + j0 + (v & 7);
        const float4* sw = (const float4*)(Whh + (size_t)grow * H + s * 8);
        Ws[v * 128 + (s ^ (v & 7))] = pack8(sw[0], sw[1]);
    }

    const int w = tid >> 6, lane = tid & 63;
    const int m = w & 3, kh = w >> 2;          // wave = (m-tile, K-half)
    const int lr = lane & 15, lg = lane >> 4;
    const int vx = lr & 7;

    const int b_e  = tid >> 3;                 // 0..63
    const int jc_e = tid & 7;
    const int hj   = j0 + jc_e;
    float breg[4];
    #pragma unroll
    for (int qq = 0; qq < 4; ++qq)
        breg[qq] = bih[qq * H + hj] + bhh[qq * H + hj];
    float creg = cbuf[b_e * H + hj];
    __syncthreads();

    int sl = t0 % NSLOT;                       // slot holding h_{t0}

    for (int tc8 = 0; tc8 < TC; tc8 += 8) {
        float oreg[8];
        #pragma unroll
        for (int p = 0; p < 8; ++p) {
            const int tcs    = tc8 + p;
            const int target = t0 + tcs;

            float xpv[4];
            #pragma unroll
            for (int qq = 0; qq < 4; ++qq)
                xpv[qq] = bf2f(xproj[((size_t)tcs * B + b_e) * G4
                                     + qq * H + hj]);

            const unsigned short* hc = hchain + (size_t)sl * (B * H);
            const int sln = (sl + 1 == NSLOT) ? 0 : sl + 1;
            unsigned short* hn_buf = hchain + (size_t)sln * (B * H);

            while (true) {
                int fv = __hip_atomic_load(&flags[(kh * 64 + lane) * FSTR],
                            __ATOMIC_RELAXED, __HIP_MEMORY_SCOPE_AGENT);
                if (__all(fv >= target)) break;
                __builtin_amdgcn_s_sleep(1);
            }

            __builtin_amdgcn_s_setprio(1);
            f32x4 acc0 = {}, acc1 = {};
            #pragma unroll
            for (int ks = 0; ks < 16; ++ks) {
                int s = kh * 64 + ks * 4 + lg;         // K-slice 0..127
                bf16x8 av = *(const bf16x8*)(hc
                    + ((size_t)s * 64 + m * 16 + lr) * 8);
                bf16x8 bw0 = Ws[lr * 128 + (s ^ vx)];
                bf16x8 bw1 = Ws[(16 + lr) * 128 + (s ^ vx)];
                acc0 = __builtin_amdgcn_mfma_f32_16x16x32_bf16(av, bw0, acc0,
                                                               0, 0, 0);
                acc1 = __builtin_amdgcn_mfma_f32_16x16x32_bf16(av, bw1, acc1,
                                                               0, 0, 0);
            }
            __builtin_amdgcn_s_setprio(0);
            #pragma unroll
            for (int r = 0; r < 4; ++r) {
                gst[kh][m * 16 + lg * 4 + r][lr]      = acc0[r];
                gst[kh][m * 16 + lg * 4 + r][16 + lr] = acc1[r];
            }
            __syncthreads();   // barrier A: gst join

            {
                float g[4];
                #pragma unroll
                for (int qq = 0; qq < 4; ++qq)
                    g[qq] = gst[0][b_e][qq * 8 + jc_e]
                          + gst[1][b_e][qq * 8 + jc_e]
                          + breg[qq] + xpv[qq];
                float ig = sigm_f(g[0]);
                float fg = sigm_f(g[1]);
                float gg = tanh_f(g[2]);
                float og = sigm_f(g[3]);
                float cn = fg * creg + ig * gg;
                float hnv = og * tanh_f(cn);
                creg = cn;
                oreg[p] = hnv;
                unsigned my = (unsigned)f2bf(hnv);
                unsigned ot = __shfl_xor(my, 1);
                if ((lane & 1) == 0) {
                    unsigned u = my | (ot << 16);
                    unsigned* dst = (unsigned*)(hn_buf
                        + (size_t)(jb * 64 + b_e) * 8 + jc_e);  // jc_e even
                    __hip_atomic_store(dst, u, __ATOMIC_RELAXED,
                                       __HIP_MEMORY_SCOPE_AGENT);
                }
            }
            __syncthreads();   // barrier B: drains all publish stores

            if (tid == 0)
                __hip_atomic_store(&flags[jb * FSTR], target + 1,
                                   __ATOMIC_RELAXED, __HIP_MEMORY_SCOPE_AGENT);
            sl = sln;
        }
        #pragma unroll
        for (int p = 0; p < 8; ++p) {
            int t = t0 + tc8 + p;
            outputs[((size_t)b_e * T + t) * H + hj] = oreg[p];
        }
    }

    cbuf[b_e * H + hj] = creg;
}

// ---------------------------------------------------------------------------
// init h slot 0 (producer-major), c, and flags in one kernel
__global__ __launch_bounds__(256) void init_state(
    const float* __restrict__ h0, const float* __restrict__ c0,
    unsigned short* __restrict__ hb, float* __restrict__ cb,
    int* __restrict__ flags)
{
    int i = blockIdx.x * 256 + threadIdx.x;    // 0..65535
    int b = i >> 10, j = i & 1023;
    hb[(size_t)(j >> 3) * 512 + b * 8 + (j & 7)] = f2bf(h0[i]);
    cb[i] = c0[i];
    if (blockIdx.x == 0 && threadIdx.x < NBLK)
        __hip_atomic_store(&flags[threadIdx.x * FSTR], 0,
                           __ATOMIC_RELAXED, __HIP_MEMORY_SCOPE_AGENT);
}

__global__ __launch_bounds__(256) void finalize(
    const float* __restrict__ outputs, const float* __restrict__ cfin,
    float* __restrict__ outh, float* __restrict__ outc)
{
    int i = blockIdx.x * 256 + threadIdx.x;    // 0..65535
    int b = i >> 10, j = i & 1023;
    outh[i] = outputs[((size_t)b * T + (T - 1)) * H + j];
    outc[i] = cfin[i];
}

// ---------------------------------------------------------------------------
extern "C" void kernel_launch(void* const* d_in, const int* in_sizes, int n_in,
                              void* d_out, int out_size, void* d_ws, size_t ws_size,
                              hipStream_t stream)
{
    const int*   tgt = (const int*)  d_in[0];
    const float* h0  = (const float*)d_in[1];
    const float* c0  = (const float*)d_in[2];
    const float* emb = (const float*)d_in[5];
    const float* Wih = (const float*)d_in[6];
    const float* Whh = (const float*)d_in[7];
    const float* bih = (const float*)d_in[8];
    const float* bhh = (const float*)d_in[9];

    float* out     = (float*)d_out;
    float* outputs = out;                                  // [B][T][H]
    float* out_h   = out + (size_t)B * T * H;
    float* out_c   = out_h + B * H;

    // ws layout — ~42.5 MB
    unsigned short* xp0    = (unsigned short*)d_ws;            // TC*B*G4
    unsigned short* xp1    = xp0 + (size_t)TC * B * G4;        // TC*B*G4
    unsigned short* hchain = xp1 + (size_t)TC * B * G4;        // NSLOT*B*H
    float*          cbuf   = (float*)(hchain + (size_t)NSLOT * B * H);
    int*            flags  = (int*)(cbuf + (size_t)B * H);     // NBLK*FSTR
    unsigned short* xp[2]  = { xp0, xp1 };

    init_state<<<(B * H) / 256, 256, 0, stream>>>(h0, c0, hchain, cbuf, flags);

    // prologue: chunk 0's x_proj on the full machine
    gemm_xproj<<<(TC * B / 128) * (G4 / 128), 256, 0, stream>>>(
        tgt, emb, Wih, xp[0], 0);

    for (int ci = 0; ci < NCH; ++ci) {
        int t0  = ci * TC;
        int t0n = (ci + 1) * TC;
        int dg  = (ci + 1 < NCH) ? 1 : 0;
        const unsigned short* xc = xp[ci & 1];
        unsigned short*       xn = xp[(ci + 1) & 1];
        void* args[] = { (void*)&xc, (void*)&Whh, (void*)&bih, (void*)&bhh,
                         (void*)&hchain, (void*)&cbuf, (void*)&outputs,
                         (void*)&flags, (void*)&t0,
                         (void*)&tgt, (void*)&emb, (void*)&Wih,
                         (void*)&xn, (void*)&t0n, (void*)&dg };
        hipLaunchCooperativeKernel((void*)lstm_fused, dim3(2 * NBLK),
                                   dim3(512), args, 0, stream);
    }
    finalize<<<(B * H) / 256, 256, 0, stream>>>(outputs, cbuf, out_h, out_c);
}

// Round 22
// 1216.779 us; speedup vs baseline: 1.0388x; 1.0388x over previous
//
#include <hip/hip_runtime.h>
#include <hip/hip_bf16.h>
#include <math.h>

#define B    64
#define T    256
#define H    1024
#define G4   4096
#define TC   32           // timesteps per x_proj chunk (double-buffered)
#define NCH  (T / TC)
#define NBLK 128          // recurrence blocks (8 h-cols each)
#define NSLOT (TC + 1)    // hchain slots; slot(t) = t % NSLOT
#define FSTR 16           // flag stride in ints (64B apart)

typedef __attribute__((ext_vector_type(8))) short bf16x8;
typedef __attribute__((ext_vector_type(4))) float f32x4;

__device__ __forceinline__ unsigned short f2bf(float x) {
    union { float f; unsigned u; } v; v.f = x;
    unsigned r = v.u + 0x7fffu + ((v.u >> 16) & 1u);   // RNE
    return (unsigned short)(r >> 16);
}
__device__ __forceinline__ float bf2f(unsigned short s) {
    union { unsigned u; float f; } v; v.u = ((unsigned)s) << 16;
    return v.f;
}
__device__ __forceinline__ float sigm_f(float x) {
    return 1.f / (1.f + __expf(-x));
}
__device__ __forceinline__ float tanh_f(float x) {
    float e = __expf(2.f * x);
    return (e - 1.f) / (e + 1.f);
}

// ---------------------------------------------------------------------------
__global__ __launch_bounds__(256) void cast_f32_bf16(
    const float* __restrict__ src, unsigned short* __restrict__ dst, int n8)
{
    int i = blockIdx.x * 256 + threadIdx.x;
    if (i >= n8) return;
    const float4* s = (const float4*)(src + (size_t)i * 8);
    float4 a = s[0], b = s[1];
    bf16x8 o;
    o[0] = f2bf(a.x); o[1] = f2bf(a.y); o[2] = f2bf(a.z); o[3] = f2bf(a.w);
    o[4] = f2bf(b.x); o[5] = f2bf(b.y); o[6] = f2bf(b.z); o[7] = f2bf(b.w);
    *(bf16x8*)(dst + (size_t)i * 8) = o;
}

// ---------------------------------------------------------------------------
// one 128x128 x_proj tile with the embedding gather + f32->bf16 cast FUSED
// into the A staging (proven r2 tile structure otherwise). Runs with 256
// threads (t256); barrier-uniform per block. LDS: AsB = As(16KB)+Bs(16KB),
// toks = 128 ints.
// ---------------------------------------------------------------------------
__device__ __forceinline__ void xproj_tile(
    const int* __restrict__ tgt, const float* __restrict__ emb,
    const unsigned short* __restrict__ Bt, unsigned short* __restrict__ C,
    int t0, int brow, int bcol,
    unsigned short* AsB, int* toks, int t256)
{
    unsigned short* As = AsB;
    unsigned short* Bs = AsB + 128 * 64;
    const int w = t256 >> 6, lane = t256 & 63;
    const int wr = w >> 1, wc = w & 1;
    const int lr = lane & 15, lg = lane >> 4;

    if (t256 < 128) {
        int r = brow + t256;                   // A row = tc*B + b
        toks[t256] = tgt[(r & 63) * T + t0 + (r >> 6)];
    }
    __syncthreads();

    f32x4 acc[4][4] = {};

    for (int kc = 0; kc < H; kc += 64) {
        if (kc) __syncthreads();
        #pragma unroll
        for (int i = 0; i < 4; ++i) {
            int sf  = i * 256 + t256;
            int row = sf >> 3, s = sf & 7;
            int col = kc + s * 8;
            const float4* sa = (const float4*)(emb
                + (size_t)toks[row] * H + col);
            float4 a0 = sa[0], a1 = sa[1];
            bf16x8 av;
            av[0] = f2bf(a0.x); av[1] = f2bf(a0.y);
            av[2] = f2bf(a0.z); av[3] = f2bf(a0.w);
            av[4] = f2bf(a1.x); av[5] = f2bf(a1.y);
            av[6] = f2bf(a1.z); av[7] = f2bf(a1.w);
            *(bf16x8*)(As + row * 64 + ((s ^ (row & 7)) * 8)) = av;
            *(bf16x8*)(Bs + row * 64 + ((s ^ (row & 7)) * 8)) =
                *(const bf16x8*)(Bt + (size_t)(bcol + row) * H + col);
        }
        __syncthreads();
        #pragma unroll
        for (int kk = 0; kk < 2; ++kk) {
            bf16x8 af[4], bv[4];
            #pragma unroll
            for (int m = 0; m < 4; ++m) {
                int row = wr * 64 + m * 16 + lr;
                int s   = kk * 4 + lg;
                af[m] = *(const bf16x8*)(As + row * 64 + ((s ^ (row & 7)) * 8));
            }
            #pragma unroll
            for (int n = 0; n < 4; ++n) {
                int row = wc * 64 + n * 16 + lr;
                int s   = kk * 4 + lg;
                bv[n] = *(const bf16x8*)(Bs + row * 64 + ((s ^ (row & 7)) * 8));
            }
            #pragma unroll
            for (int m = 0; m < 4; ++m)
                #pragma unroll
                for (int n = 0; n < 4; ++n)
                    acc[m][n] = __builtin_amdgcn_mfma_f32_16x16x32_bf16(
                        af[m], bv[n], acc[m][n], 0, 0, 0);
        }
    }
    #pragma unroll
    for (int m = 0; m < 4; ++m)
        #pragma unroll
        for (int n = 0; n < 4; ++n)
            #pragma unroll
            for (int r = 0; r < 4; ++r) {
                int row = brow + wr * 64 + m * 16 + lg * 4 + r;
                int col = bcol + wc * 64 + n * 16 + lr;
                C[(size_t)row * G4 + col] = f2bf(acc[m][n][r]);
            }
    __syncthreads();   // LDS safe for next tile
}

// ---------------------------------------------------------------------------
// standalone prologue GEMM for chunk 0: 512 blocks x 256 thr, 1 tile each
// ---------------------------------------------------------------------------
__global__ __launch_bounds__(256) void gemm_xproj(
    const int* __restrict__ tgt, const float* __restrict__ emb,
    const unsigned short* __restrict__ wih, unsigned short* __restrict__ xp,
    int t0)
{
    __shared__ __align__(16) unsigned char smem[33280];
    unsigned short* AsB = (unsigned short*)smem;
    int* toks = (int*)(smem + 32768);
    int tile = blockIdx.x;                      // 0..511
    xproj_tile(tgt, emb, wih, xp, t0,
               (tile >> 5) * 128, (tile & 31) * 128, AsB, toks, threadIdx.x);
}

// ---------------------------------------------------------------------------
// fused dual-role cooperative kernel:
//  blocks 0..127  — r17 recurrence for chunk at t0 (code verbatim; hchain
//                   slot = t % 33, removing the inter-launch copy);
//  blocks 128..255 — next chunk's x_proj GEMM into xpn (2 sub-GEMMs of 4
//                   waves; 512 tiles over 128 blocks x 2 subs x 2 rounds).
// Roles touch disjoint buffers; recurrence handoff protocol unchanged.
// ---------------------------------------------------------------------------
__global__ __launch_bounds__(512) void lstm_fused(
    const unsigned short* __restrict__ xproj,  // [TC][B][4096] bf16 (cur)
    const unsigned short* __restrict__ whh,    // [4096][1024] bf16
    const float* __restrict__ bih, const float* __restrict__ bhh,
    unsigned short* __restrict__ hchain,       // [NSLOT][NBLK][64][8] bf16
    float* __restrict__ cbuf,                  // [B][H] f32
    float* __restrict__ outputs,               // [B][T][H] f32
    int* __restrict__ flags,                   // [NBLK*FSTR]
    int t0,
    const int* __restrict__ tgt, const float* __restrict__ emb,
    const unsigned short* __restrict__ wih,
    unsigned short* __restrict__ xpn,          // next chunk's xproj out
    int t0n, int do_gemm)
{
    __shared__ __align__(16) unsigned char smem[83968];
    const int tid = threadIdx.x;
    const int bid = blockIdx.x;

    if (bid >= NBLK) {
        // ================= GEMM role =================
        if (!do_gemm) return;
        const int sub  = tid >> 8;             // 0,1
        const int t256 = tid & 255;
        unsigned char* base = smem + sub * 33280;
        unsigned short* AsB = (unsigned short*)base;
        int* toks = (int*)(base + 32768);
        const int gb = bid - NBLK;             // 0..127
        #pragma unroll
        for (int i = 0; i < 2; ++i) {
            int tile = i * 256 + gb * 2 + sub; // 0..511
            xproj_tile(tgt, emb, wih, xpn, t0n,
                       (tile >> 5) * 128, (tile & 31) * 128, AsB, toks, t256);
        }
        return;
    }

    // ================= recurrence role (r17 verbatim) =================
    bf16x8* Ws = (bf16x8*)smem;                        // 64 KB
    float (*gst)[64][36] = (float (*)[64][36])(smem + 65536);  // 18.4 KB

    const int jb = bid;
    const int j0 = jb * 8;

    #pragma unroll
    for (int it = 0; it < 8; ++it) {
        int f = it * 512 + tid;                // 16B-slot id, 0..4095
        int v = f >> 7, s = f & 127;
        int grow = (v >> 3) * H + j0 + (v & 7);
        Ws[v * 128 + (s ^ (v & 7))] =
            *(const bf16x8*)(whh + (size_t)grow * H + s * 8);
    }

    const int w = tid >> 6, lane = tid & 63;
    const int m = w & 3, kh = w >> 2;          // wave = (m-tile, K-half)
    const int lr = lane & 15, lg = lane >> 4;
    const int vx = lr & 7;

    const int b_e  = tid >> 3;                 // 0..63
    const int jc_e = tid & 7;
    const int hj   = j0 + jc_e;
    float breg[4];
    #pragma unroll
    for (int qq = 0; qq < 4; ++qq)
        breg[qq] = bih[qq * H + hj] + bhh[qq * H + hj];
    float creg = cbuf[b_e * H + hj];
    __syncthreads();

    int sl = t0 % NSLOT;                       // slot holding h_{t0}

    for (int tc8 = 0; tc8 < TC; tc8 += 8) {
        float oreg[8];
        #pragma unroll
        for (int p = 0; p < 8; ++p) {
            const int tcs    = tc8 + p;
            const int target = t0 + tcs;

            float xpv[4];
            #pragma unroll
            for (int qq = 0; qq < 4; ++qq)
                xpv[qq] = bf2f(xproj[((size_t)tcs * B + b_e) * G4
                                     + qq * H + hj]);

            const unsigned short* hc = hchain + (size_t)sl * (B * H);
            const int sln = (sl + 1 == NSLOT) ? 0 : sl + 1;
            unsigned short* hn_buf = hchain + (size_t)sln * (B * H);

            while (true) {
                int fv = __hip_atomic_load(&flags[(kh * 64 + lane) * FSTR],
                            __ATOMIC_RELAXED, __HIP_MEMORY_SCOPE_AGENT);
                if (__all(fv >= target)) break;
                __builtin_amdgcn_s_sleep(1);
            }

            __builtin_amdgcn_s_setprio(1);
            f32x4 acc0 = {}, acc1 = {};
            #pragma unroll
            for (int ks = 0; ks < 16; ++ks) {
                int s = kh * 64 + ks * 4 + lg;         // K-slice 0..127
                bf16x8 av = *(const bf16x8*)(hc
                    + ((size_t)s * 64 + m * 16 + lr) * 8);
                bf16x8 bw0 = Ws[lr * 128 + (s ^ vx)];
                bf16x8 bw1 = Ws[(16 + lr) * 128 + (s ^ vx)];
                acc0 = __builtin_amdgcn_mfma_f32_16x16x32_bf16(av, bw0, acc0,
                                                               0, 0, 0);
                acc1 = __builtin_amdgcn_mfma_f32_16x16x32_bf16(av, bw1, acc1,
                                                               0, 0, 0);
            }
            __builtin_amdgcn_s_setprio(0);
            #pragma unroll
            for (int r = 0; r < 4; ++r) {
                gst[kh][m * 16 + lg * 4 + r][lr]      = acc0[r];
                gst[kh][m * 16 + lg * 4 + r][16 + lr] = acc1[r];
            }
            __syncthreads();   // barrier A: gst join

            {
                float g[4];
                #pragma unroll
                for (int qq = 0; qq < 4; ++qq)
                    g[qq] = gst[0][b_e][qq * 8 + jc_e]
                          + gst[1][b_e][qq * 8 + jc_e]
                          + breg[qq] + xpv[qq];
                float ig = sigm_f(g[0]);
                float fg = sigm_f(g[1]);
                float gg = tanh_f(g[2]);
                float og = sigm_f(g[3]);
                float cn = fg * creg + ig * gg;
                float hnv = og * tanh_f(cn);
                creg = cn;
                oreg[p] = hnv;
                unsigned my = (unsigned)f2bf(hnv);
                unsigned ot = __shfl_xor(my, 1);
                if ((lane & 1) == 0) {
                    unsigned u = my | (ot << 16);
                    unsigned* dst = (unsigned*)(hn_buf
                        + (size_t)(jb * 64 + b_e) * 8 + jc_e);  // jc_e even
                    __hip_atomic_store(dst, u, __ATOMIC_RELAXED,
                                       __HIP_MEMORY_SCOPE_AGENT);
                }
            }
            __syncthreads();   // barrier B: drains all publish stores

            if (tid == 0)
                __hip_atomic_store(&flags[jb * FSTR], target + 1,
                                   __ATOMIC_RELAXED, __HIP_MEMORY_SCOPE_AGENT);
            sl = sln;
        }
        #pragma unroll
        for (int p = 0; p < 8; ++p) {
            int t = t0 + tc8 + p;
            outputs[((size_t)b_e * T + t) * H + hj] = oreg[p];
        }
    }

    cbuf[b_e * H + hj] = creg;
}

// ---------------------------------------------------------------------------
// init h slot 0 in producer-major layout: slot0[j>>3][b][j&7] = h0[b][j]
__global__ __launch_bounds__(256) void init_state(
    const float* __restrict__ h0, const float* __restrict__ c0,
    unsigned short* __restrict__ hb, float* __restrict__ cb)
{
    int i = blockIdx.x * 256 + threadIdx.x;    // 0..65535
    int b = i >> 10, j = i & 1023;
    hb[(size_t)(j >> 3) * 512 + b * 8 + (j & 7)] = f2bf(h0[i]);
    cb[i] = c0[i];
}

__global__ __launch_bounds__(128) void reset_flags(int* __restrict__ flags)
{
    __hip_atomic_store(&flags[threadIdx.x * FSTR], 0,
                       __ATOMIC_RELAXED, __HIP_MEMORY_SCOPE_AGENT);
}

__global__ __launch_bounds__(256) void finalize(
    const float* __restrict__ outputs, const float* __restrict__ cfin,
    float* __restrict__ outh, float* __restrict__ outc)
{
    int i = blockIdx.x * 256 + threadIdx.x;    // 0..65535
    int b = i >> 10, j = i & 1023;
    outh[i] = outputs[((size_t)b * T + (T - 1)) * H + j];
    outc[i] = cfin[i];
}

// ---------------------------------------------------------------------------
extern "C" void kernel_launch(void* const* d_in, const int* in_sizes, int n_in,
                              void* d_out, int out_size, void* d_ws, size_t ws_size,
                              hipStream_t stream)
{
    const int*   tgt = (const int*)  d_in[0];
    const float* h0  = (const float*)d_in[1];
    const float* c0  = (const float*)d_in[2];
    const float* emb = (const float*)d_in[5];
    const float* Wih = (const float*)d_in[6];
    const float* Whh = (const float*)d_in[7];
    const float* bih = (const float*)d_in[8];
    const float* bhh = (const float*)d_in[9];

    float* out     = (float*)d_out;
    float* outputs = out;                                  // [B][T][H]
    float* out_h   = out + (size_t)B * T * H;
    float* out_c   = out_h + B * H;

    // ws layout — ~55 MB
    unsigned short* xp0    = (unsigned short*)d_ws;            // TC*B*G4
    unsigned short* xp1    = xp0 + (size_t)TC * B * G4;        // TC*B*G4
    unsigned short* wih    = xp1 + (size_t)TC * B * G4;        // G4*H
    unsigned short* whh    = wih + (size_t)G4 * H;             // G4*H
    unsigned short* hchain = whh + (size_t)G4 * H;             // NSLOT*B*H
    float*          cbuf   = (float*)(hchain + (size_t)NSLOT * B * H);
    int*            flags  = (int*)(cbuf + (size_t)B * H);     // NBLK*FSTR
    unsigned short* xp[2]  = { xp0, xp1 };

    cast_f32_bf16<<<2048, 256, 0, stream>>>(Wih, wih, (G4 * H) / 8);
    cast_f32_bf16<<<2048, 256, 0, stream>>>(Whh, whh, (G4 * H) / 8);
    init_state<<<(B * H) / 256, 256, 0, stream>>>(h0, c0, hchain, cbuf);
    reset_flags<<<1, NBLK, 0, stream>>>(flags);

    // prologue: chunk 0's x_proj on the full machine
    gemm_xproj<<<(TC * B / 128) * (G4 / 128), 256, 0, stream>>>(
        tgt, emb, wih, xp[0], 0);

    for (int ci = 0; ci < NCH; ++ci) {
        int t0  = ci * TC;
        int t0n = (ci + 1) * TC;
        int dg  = (ci + 1 < NCH) ? 1 : 0;
        const unsigned short* xc = xp[ci & 1];
        unsigned short*       xn = xp[(ci + 1) & 1];
        void* args[] = { (void*)&xc, (void*)&whh, (void*)&bih, (void*)&bhh,
                         (void*)&hchain, (void*)&cbuf, (void*)&outputs,
                         (void*)&flags, (void*)&t0,
                         (void*)&tgt, (void*)&emb, (void*)&wih,
                         (void*)&xn, (void*)&t0n, (void*)&dg };
        hipLaunchCooperativeKernel((void*)lstm_fused, dim3(2 * NBLK),
                                   dim3(512), args, 0, stream);
    }
    finalize<<<(B * H) / 256, 256, 0, stream>>>(outputs, cbuf, out_h, out_c);
}